// Round 1
// baseline (267.768 us; speedup 1.0000x reference)
//
#include <hip/hip_runtime.h>
#include <math.h>
#include <stdint.h>

// Video Swin shifted-window attention, fully fused.
// One block per window (2048 blocks x 512 threads = 8 waves).
// All matmuls via v_mfma_f32_16x16x32_bf16, fp32 accum.
//
// Orientations chosen so every LDS fragment access is contiguous 8/16B:
//   QKV:  C' = Wqkv(384x128) @ X^T           -> q,k stored [tok][ch] (b64), vT stored [d][tok] (scalar)
//   attn: S^T = K @ Q^T  (softmax over rows of S^T = shfl_xor 16/32)
//         P^T C-frags store contiguously into P_lds[i][j]
//   PV:   O^T = V^T @ P^T   (A from vT_lds, B from P_lds, both ds_read_b128)
//   proj: y^T = Wproj @ O^T -> C-frag = 4 contiguous fp32 -> dwordx4 global store
// Shift mask computed analytically; rpb gathered to ws by prep kernel.

#define LOG2E  1.4426950408889634f
#define QSCALE 0.17677669529663689f

typedef __attribute__((ext_vector_type(8))) short bf16x8;
typedef __attribute__((ext_vector_type(4))) float f32x4;

__device__ __forceinline__ unsigned short f2bf(float f) {
    unsigned int u = __builtin_bit_cast(unsigned int, f);
    u = (u + 0x7FFFu + ((u >> 16) & 1u)) >> 16;
    return (unsigned short)u;
}

// token region code for the shifted-window mask.
// t -> (pd, ph, pw); boundary at p >= WIN-SHIFT: d:1, h:4, w:4.
__device__ __forceinline__ int tok_code(int t) {
    int pd = t / 49;
    int r  = t - pd * 49;
    int ph = r / 7;
    int pw = r - ph * 7;
    return (pd >= 1 ? 1 : 0) | (ph >= 4 ? 2 : 0) | (pw >= 4 ? 4 : 0);
}

// XOR-swizzled element offset inside a [rows][128]-bf16 LDS tile (16B chunks).
__device__ __forceinline__ int swz(int row, int col) {
    return row * 128 + (((col >> 3) ^ (row & 7)) << 3) + (col & 7);
}

// ---------------- prep: weights -> bf16, rpb gather ----------------
__global__ void prep_kernel(const float* __restrict__ qkv_w,
                            const float* __restrict__ proj_w,
                            const float* __restrict__ rpb_table,
                            const int*   __restrict__ rel_index,
                            unsigned short* __restrict__ wqkv,
                            unsigned short* __restrict__ wproj,
                            float* __restrict__ rpbg) {
    int tid = blockIdx.x * blockDim.x + threadIdx.x;
    int stride = gridDim.x * blockDim.x;
    for (int i = tid; i < 384 * 128; i += stride) wqkv[i]  = f2bf(qkv_w[i]);
    for (int i = tid; i < 128 * 128; i += stride) wproj[i] = f2bf(proj_w[i]);
    for (int i = tid; i < 4 * 98 * 98; i += stride) {
        int h = i / 9604;
        int ij = i - h * 9604;
        rpbg[i] = rpb_table[rel_index[ij] * 4 + h];
    }
}

// ---------------- main fused kernel ----------------
__global__ __launch_bounds__(512)
void swin_main(const float* __restrict__ x,
               const float* __restrict__ qkv_b,
               const float* __restrict__ proj_b,
               const unsigned short* __restrict__ wqkv,
               const unsigned short* __restrict__ wproj,
               const float* __restrict__ rpbg,
               float* __restrict__ out)
{
    extern __shared__ unsigned short lds[];
    unsigned short* q_lds  = lds;            // [112][128] bf16, swizzled
    unsigned short* k_lds  = lds + 14336;    // [112][128]
    unsigned short* vT_lds = lds + 28672;    // [128][128]  (cols 112..127 stay 0)
    unsigned short* p_lds  = lds + 45056;    // [8 waves][16][128] (cols 112..127 stay 0)
    unsigned short* xo_lds = lds + 61440;    // [112][128]  x during QKV, O afterwards

    const int b    = blockIdx.x;
    const int tid  = threadIdx.x;
    const int wv   = tid >> 6;
    const int lane = tid & 63;
    const int l4   = lane >> 4;   // 0..3
    const int lc   = lane & 15;   // 0..15

    // zero vT + P (contiguous 32768 ushorts = 64KB)
    {
        uint4 z; z.x = z.y = z.z = z.w = 0u;
        for (int i = tid * 8; i < 32768; i += 512 * 8)
            *(uint4*)(vT_lds + i) = z;
    }

    // stage x -> xo_lds as bf16 (pad rows 98..111 zeroed)
    {
        const float* xb = x + (size_t)b * 12544;
        for (int idx = tid; idx < 3584; idx += 512) {
            int tok = idx >> 5;
            int c   = (idx & 31) << 2;
            float4 v;
            if (tok < 98) v = *(const float4*)(xb + tok * 128 + c);
            else { v.x = 0.f; v.y = 0.f; v.z = 0.f; v.w = 0.f; }
            ushort4 hv;
            hv.x = f2bf(v.x); hv.y = f2bf(v.y); hv.z = f2bf(v.z); hv.w = f2bf(v.w);
            *(ushort4*)(xo_lds + swz(tok, c)) = hv;
        }
    }
    __syncthreads();

    // ---- Phase 1: QKV' = Wqkv @ X^T  (wave wv owns chtiles {wv, wv+8, wv+16}) ----
    {
        bf16x8 wfrag[3][4];
        f32x4  bias[3];
#pragma unroll
        for (int g = 0; g < 3; ++g) {
            int ct = wv + 8 * g;
#pragma unroll
            for (int kt = 0; kt < 4; ++kt)
                wfrag[g][kt] = *(const bf16x8*)(wqkv + (ct * 16 + lc) * 128 + kt * 32 + l4 * 8);
#pragma unroll
            for (int r = 0; r < 4; ++r)
                bias[g][r] = qkv_b[ct * 16 + l4 * 4 + r];
        }
#pragma unroll
        for (int t = 0; t < 7; ++t) {
            bf16x8 xfrag[4];
#pragma unroll
            for (int kt = 0; kt < 4; ++kt)
                xfrag[kt] = *(bf16x8*)(xo_lds + swz(t * 16 + lc, kt * 32 + l4 * 8));
            int tok = t * 16 + lc;
#pragma unroll
            for (int g = 0; g < 3; ++g) {
                f32x4 acc = bias[g];
#pragma unroll
                for (int kt = 0; kt < 4; ++kt)
                    acc = __builtin_amdgcn_mfma_f32_16x16x32_bf16(wfrag[g][kt], xfrag[kt], acc, 0, 0, 0);
                int chb = (wv + 8 * g) * 16 + l4 * 4;  // C' rows = channels
                if (g == 0) {            // q: fold softmax scale
                    ushort4 hv;
                    hv.x = f2bf(acc[0] * QSCALE); hv.y = f2bf(acc[1] * QSCALE);
                    hv.z = f2bf(acc[2] * QSCALE); hv.w = f2bf(acc[3] * QSCALE);
                    *(ushort4*)(q_lds + swz(tok, chb)) = hv;
                } else if (g == 1) {     // k
                    ushort4 hv;
                    hv.x = f2bf(acc[0]); hv.y = f2bf(acc[1]);
                    hv.z = f2bf(acc[2]); hv.w = f2bf(acc[3]);
                    *(ushort4*)(k_lds + swz(tok, chb - 128)) = hv;
                } else {                 // v -> vT[d][tok] (scalar stores)
                    int d0 = chb - 256;
#pragma unroll
                    for (int r = 0; r < 4; ++r)
                        vT_lds[swz(d0 + r, tok)] = f2bf(acc[r]);
                }
            }
        }
    }
    __syncthreads();

    // ---- Phase 2: attention (wave -> head h = wv>>1, half = wv&1) ----
    const int h = wv >> 1;
    const int wi = b & 255;
    const unsigned int wmask_e =
        ((wi >> 6) == 3 ? 1u : 0u) | (((wi >> 3) & 7) == 7 ? 2u : 0u) | ((wi & 7) == 7 ? 4u : 0u);

    unsigned int jcp[7];   // packed region codes for this lane's 4 S^T rows, per jt
#pragma unroll
    for (int jt = 0; jt < 7; ++jt) {
        int jb = jt * 16 + l4 * 4;
        unsigned int p = 0;
#pragma unroll
        for (int r = 0; r < 4; ++r) p |= (unsigned)tok_code(jb + r < 98 ? jb + r : 0) << (8 * r);
        jcp[jt] = p;
    }

    const int itb = (wv & 1) ? 4 : 0;
    const int ite = (wv & 1) ? 7 : 4;
    unsigned short* myP = p_lds + wv * 2048;

    for (int it = itb; it < ite; ++it) {
        const int i_tok = it * 16 + lc;
        const bool ivalid = (i_tok < 98);
        const bf16x8 qfrag = *(bf16x8*)(q_lds + swz(i_tok, h * 32 + l4 * 8));
        const int ci = tok_code(ivalid ? i_tok : 0);

        f32x4 s[7];
#pragma unroll
        for (int jt = 0; jt < 7; ++jt) {
            int jb = jt * 16 + l4 * 4;
            f32x4 c;
#pragma unroll
            for (int r = 0; r < 4; ++r) {
                int j = jb + r;
                float cv;
                if (j >= 98) cv = -INFINITY;           // pad keys -> P = 0
                else if (ivalid) {
                    unsigned int jc = (jcp[jt] >> (8 * r)) & 255u;
                    cv = rpbg[h * 9604 + i_tok * 98 + j]
                       + (((jc ^ (unsigned)ci) & wmask_e) ? -100.f : 0.f);
                } else cv = 0.f;                        // pad queries: finite garbage
                c[r] = cv;
            }
            bf16x8 kfrag = *(bf16x8*)(k_lds + swz(jt * 16 + lc, h * 32 + l4 * 8));
            s[jt] = __builtin_amdgcn_mfma_f32_16x16x32_bf16(kfrag, qfrag, c, 0, 0, 0);
        }

        // softmax over j (rows of S^T): per-lane partial, then shfl_xor 16/32
        float m = -INFINITY;
#pragma unroll
        for (int jt = 0; jt < 7; ++jt)
#pragma unroll
            for (int r = 0; r < 4; ++r) m = fmaxf(m, s[jt][r]);
        m = fmaxf(m, __shfl_xor(m, 16));
        m = fmaxf(m, __shfl_xor(m, 32));

        float lsum = 0.f;
#pragma unroll
        for (int jt = 0; jt < 7; ++jt) {
            float p0 = exp2f((s[jt][0] - m) * LOG2E);
            float p1 = exp2f((s[jt][1] - m) * LOG2E);
            float p2 = exp2f((s[jt][2] - m) * LOG2E);
            float p3 = exp2f((s[jt][3] - m) * LOG2E);
            lsum += (p0 + p1) + (p2 + p3);
            ushort4 hv;
            hv.x = f2bf(p0); hv.y = f2bf(p1); hv.z = f2bf(p2); hv.w = f2bf(p3);
            *(ushort4*)(myP + swz(lc, jt * 16 + l4 * 4)) = hv;   // P^T -> [i][j]
        }
        lsum += __shfl_xor(lsum, 16);
        lsum += __shfl_xor(lsum, 32);

        // O^T = V^T @ P^T  (K = 128 incl. zero pads)
        f32x4 o0 = {0.f, 0.f, 0.f, 0.f}, o1 = {0.f, 0.f, 0.f, 0.f};
#pragma unroll
        for (int jt4 = 0; jt4 < 4; ++jt4) {
            bf16x8 pfrag = *(bf16x8*)(myP + swz(lc, jt4 * 32 + l4 * 8));
            bf16x8 va = *(bf16x8*)(vT_lds + swz(h * 32 + lc,      jt4 * 32 + l4 * 8));
            bf16x8 vb = *(bf16x8*)(vT_lds + swz(h * 32 + 16 + lc, jt4 * 32 + l4 * 8));
            o0 = __builtin_amdgcn_mfma_f32_16x16x32_bf16(va, pfrag, o0, 0, 0, 0);
            o1 = __builtin_amdgcn_mfma_f32_16x16x32_bf16(vb, pfrag, o1, 0, 0, 0);
        }
        float inv = 1.0f / lsum;
        ushort4 h0, h1;
        h0.x = f2bf(o0[0] * inv); h0.y = f2bf(o0[1] * inv);
        h0.z = f2bf(o0[2] * inv); h0.w = f2bf(o0[3] * inv);
        h1.x = f2bf(o1[0] * inv); h1.y = f2bf(o1[1] * inv);
        h1.z = f2bf(o1[2] * inv); h1.w = f2bf(o1[3] * inv);
        *(ushort4*)(xo_lds + swz(i_tok, h * 32 + l4 * 4)) = h0;       // O[i][ch]
        *(ushort4*)(xo_lds + swz(i_tok, h * 32 + 16 + l4 * 4)) = h1;
    }
    __syncthreads();

    // ---- Phase 3: y^T = Wproj @ O^T  (wave wv owns octile wv) ----
    {
        bf16x8 pw[4];
#pragma unroll
        for (int kt = 0; kt < 4; ++kt)
            pw[kt] = *(const bf16x8*)(wproj + (wv * 16 + lc) * 128 + kt * 32 + l4 * 8);
        f32x4 pbias;
#pragma unroll
        for (int r = 0; r < 4; ++r) pbias[r] = proj_b[wv * 16 + l4 * 4 + r];

        float* ob = out + (size_t)b * 12544;
#pragma unroll
        for (int t = 0; t < 7; ++t) {
            f32x4 acc = pbias;
#pragma unroll
            for (int kt = 0; kt < 4; ++kt) {
                bf16x8 of = *(bf16x8*)(xo_lds + swz(t * 16 + lc, kt * 32 + l4 * 8));
                acc = __builtin_amdgcn_mfma_f32_16x16x32_bf16(pw[kt], of, acc, 0, 0, 0);
            }
            int tok = t * 16 + lc;
            if (tok < 98) {
                float4 st; st.x = acc[0]; st.y = acc[1]; st.z = acc[2]; st.w = acc[3];
                *(float4*)(ob + tok * 128 + wv * 16 + l4 * 4) = st;
            }
        }
    }
}

extern "C" void kernel_launch(void* const* d_in, const int* in_sizes, int n_in,
                              void* d_out, int out_size, void* d_ws, size_t ws_size,
                              hipStream_t stream) {
    const float* x       = (const float*)d_in[0];
    const float* qkv_w   = (const float*)d_in[1];
    const float* qkv_b   = (const float*)d_in[2];
    const float* rpb_tab = (const float*)d_in[3];
    const float* proj_w  = (const float*)d_in[4];
    const float* proj_b  = (const float*)d_in[5];
    const int*   rel_idx = (const int*)d_in[6];
    // d_in[7] (mask) unused: reproduced analytically in-kernel.

    unsigned short* wqkv  = (unsigned short*)d_ws;                      // 384*128 bf16
    unsigned short* wproj = (unsigned short*)((char*)d_ws + 98304);     // 128*128 bf16
    float*          rpbg  = (float*)((char*)d_ws + 131072);             // 4*98*98 f32
    float*          out   = (float*)d_out;

    hipLaunchKernelGGL(prep_kernel, dim3(128), dim3(256), 0, stream,
                       qkv_w, proj_w, rpb_tab, rel_idx, wqkv, wproj, rpbg);

    const int LDS_BYTES = 151552;
    (void)hipFuncSetAttribute((const void*)swin_main,
                              hipFuncAttributeMaxDynamicSharedMemorySize, LDS_BYTES);
    hipLaunchKernelGGL(swin_main, dim3(2048), dim3(512), LDS_BYTES, stream,
                       x, qkv_b, proj_b, wqkv, wproj, rpbg, out);
}

// Round 3
// 157.144 us; speedup vs baseline: 1.7040x; 1.7040x over previous
//
#include <hip/hip_runtime.h>
#include <math.h>
#include <stdint.h>

// Video Swin shifted-window attention, fully fused, one block per window.
// Round 3: round-2 structure (1024 thr / 16 waves, 4 waves/SIMD) with
//  - PV chunk-3 fix: j=112..127 pad half of P written as zeros (no s[7] OOB)
//  - bias table as bf16 [4][112][112] (*LOG2E, -inf at j>=98): 100KB, ws-safe
//  - shift mask applied in-kernel from packed region codes

#define LOG2E   1.4426950408889634f
#define MASKNEG (-144.26950408889634f)   // -100 * LOG2E

typedef __attribute__((ext_vector_type(8))) short bf16x8;
typedef __attribute__((ext_vector_type(4))) float f32x4;

__device__ __forceinline__ unsigned short f2bf(float f) {
    unsigned int u = __builtin_bit_cast(unsigned int, f);
    u = (u + 0x7FFFu + ((u >> 16) & 1u)) >> 16;
    return (unsigned short)u;
}

// token region code for the shifted-window mask (WIN=(2,7,7), SHIFT=(1,3,3))
__device__ __forceinline__ int tok_code(int t) {
    int pd = t / 49;
    int r  = t - pd * 49;
    int ph = r / 7;
    int pw = r - ph * 7;
    return (pd >= 1 ? 1 : 0) | (ph >= 4 ? 2 : 0) | (pw >= 4 ? 4 : 0);
}

__device__ __forceinline__ float mterm(unsigned pk, int sh, unsigned ci, unsigned cls) {
    return ((((pk >> sh) & 255u) ^ ci) & cls) ? MASKNEG : 0.f;
}

// XOR-swizzled element offset inside a [rows][128]-bf16 LDS tile (16B chunks).
__device__ __forceinline__ int swz(int row, int col) {
    return row * 128 + (((col >> 3) ^ (row & 7)) << 3) + (col & 7);
}

// ---------------- prep: weights -> bf16, bias table ----------------
__global__ void prep_kernel(const float* __restrict__ qkv_w,
                            const float* __restrict__ proj_w,
                            const float* __restrict__ rpb_table,
                            const int*   __restrict__ rel_index,
                            unsigned short* __restrict__ wqkv,
                            unsigned short* __restrict__ wproj,
                            unsigned short* __restrict__ biasL) {
    int tid = blockIdx.x * blockDim.x + threadIdx.x;
    int stride = gridDim.x * blockDim.x;
    for (int i = tid; i < 384 * 128; i += stride) wqkv[i]  = f2bf(qkv_w[i]);
    for (int i = tid; i < 128 * 128; i += stride) wproj[i] = f2bf(proj_w[i]);
    // biasL[h 4][i 112][j 112] bf16, premult LOG2E; j>=98 -> -inf; i>=98 -> 0
    for (int idx = tid; idx < 4 * 112 * 112; idx += stride) {
        int h = idx / 12544; int r = idx - h * 12544;
        int i = r / 112;     int j = r - i * 112;
        float v;
        if (i < 98) v = (j < 98) ? rpb_table[rel_index[i * 98 + j] * 4 + h] * LOG2E
                                 : -INFINITY;
        else v = 0.f;
        biasL[idx] = f2bf(v);
    }
}

// ---------------- main fused kernel ----------------
__global__ __launch_bounds__(1024)
void swin_main(const float* __restrict__ x,
               const float* __restrict__ qkv_b,
               const float* __restrict__ proj_b,
               const unsigned short* __restrict__ wqkv,
               const unsigned short* __restrict__ wproj,
               const unsigned short* __restrict__ biasL,
               float* __restrict__ out)
{
    extern __shared__ unsigned short lds[];
    unsigned short* q_lds  = lds;            // [112][128] bf16, swizzled
    unsigned short* k_lds  = lds + 14336;    // [112][128]
    unsigned short* vT_lds = lds + 28672;    // [128][128] (cols 112..127 zeroed)
    unsigned short* xo_lds = lds + 45056;    // [112][128] x during QKV, O afterwards
    unsigned short* p_lds  = lds + 59392;    // [16 waves][2 buf][16][40]

    const int b    = blockIdx.x;
    const int tid  = threadIdx.x;
    const int wv   = tid >> 6;    // 0..15
    const int lane = tid & 63;
    const int l4   = lane >> 4;   // 0..3
    const int lc   = lane & 15;   // 0..15

    // zero vT pad cols 112..127 (128 rows x 16 cols = 2048 ushorts, 2/thread)
    {
        int idx2 = tid * 2;
        int row  = idx2 >> 4;
        int c    = 112 + (idx2 & 15);
        *(unsigned int*)(vT_lds + swz(row, c)) = 0u;
    }

    // stage x -> xo_lds as bf16 (pad rows 98..111 zeroed)
    {
        const float* xb = x + (size_t)b * 12544;
        for (int idx = tid; idx < 3584; idx += 1024) {
            int tok = idx >> 5;
            int c   = (idx & 31) << 2;
            float4 v;
            if (tok < 98) v = *(const float4*)(xb + tok * 128 + c);
            else { v.x = 0.f; v.y = 0.f; v.z = 0.f; v.w = 0.f; }
            ushort4 hv;
            hv.x = f2bf(v.x); hv.y = f2bf(v.y); hv.z = f2bf(v.z); hv.w = f2bf(v.w);
            *(ushort4*)(xo_lds + swz(tok, c)) = hv;
        }
    }
    __syncthreads();

    // ---- Phase 1: QKV' = Wqkv @ X^T ----
    // wave wv: column-tile ct=wv (q: 0..7 w/ scale, k: 8..15), plus half of a v tile.
    {
        const int ct = wv;
        bf16x8 wf[4];
        f32x4  bias;
        const unsigned short* wrow = wqkv + (ct * 16 + lc) * 128;
#pragma unroll
        for (int kt = 0; kt < 4; ++kt) wf[kt] = *(const bf16x8*)(wrow + kt * 32 + l4 * 8);
#pragma unroll
        for (int r = 0; r < 4; ++r) bias[r] = qkv_b[ct * 16 + l4 * 4 + r];
        const bool  isq = (ct < 8);
        const float qs  = isq ? (0.17677669529663689f * LOG2E) : 1.0f;  // scale*log2e folded
#pragma unroll
        for (int t = 0; t < 7; ++t) {
            bf16x8 xf[4];
#pragma unroll
            for (int kt = 0; kt < 4; ++kt)
                xf[kt] = *(bf16x8*)(xo_lds + swz(t * 16 + lc, kt * 32 + l4 * 8));
            f32x4 acc = bias;
#pragma unroll
            for (int kt = 0; kt < 4; ++kt)
                acc = __builtin_amdgcn_mfma_f32_16x16x32_bf16(wf[kt], xf[kt], acc, 0, 0, 0);
            int tok = t * 16 + lc;
            ushort4 hv;
            hv.x = f2bf(acc[0] * qs); hv.y = f2bf(acc[1] * qs);
            hv.z = f2bf(acc[2] * qs); hv.w = f2bf(acc[3] * qs);
            if (isq) *(ushort4*)(q_lds + swz(tok, ct * 16 + l4 * 4)) = hv;
            else     *(ushort4*)(k_lds + swz(tok, (ct - 8) * 16 + l4 * 4)) = hv;
        }
        // v: wave pair (wv>>1) owns channel block vd, halves split by wv&1
        const int vd = (wv >> 1) * 16;
        bf16x8 wf2[4];
        const unsigned short* wrow2 = wqkv + (256 + vd + lc) * 128;
#pragma unroll
        for (int kt = 0; kt < 4; ++kt) wf2[kt] = *(const bf16x8*)(wrow2 + kt * 32 + l4 * 8);
        f32x4 bias2;
#pragma unroll
        for (int r = 0; r < 4; ++r) bias2[r] = qkv_b[256 + vd + l4 * 4 + r];
        const int t0 = (wv & 1) ? 4 : 0, t1 = (wv & 1) ? 7 : 4;
        for (int t = t0; t < t1; ++t) {
            bf16x8 xf[4];
#pragma unroll
            for (int kt = 0; kt < 4; ++kt)
                xf[kt] = *(bf16x8*)(xo_lds + swz(t * 16 + lc, kt * 32 + l4 * 8));
            f32x4 acc = bias2;
#pragma unroll
            for (int kt = 0; kt < 4; ++kt)
                acc = __builtin_amdgcn_mfma_f32_16x16x32_bf16(wf2[kt], xf[kt], acc, 0, 0, 0);
            int tok = t * 16 + lc;
#pragma unroll
            for (int r = 0; r < 4; ++r)
                vT_lds[swz(vd + l4 * 4 + r, tok)] = f2bf(acc[r]);
        }
    }
    __syncthreads();

    // ---- Phase 2: attention. 28 tasks (head,i-tile) over 16 waves, 2 passes ----
    const int wi  = b & 255;
    const unsigned int cls =
        ((wi >> 6) == 3 ? 1u : 0u) | (((wi >> 3) & 7) == 7 ? 2u : 0u) | ((wi & 7) == 7 ? 4u : 0u);

    unsigned int jcp[7];   // packed region codes for this lane's 4 S^T rows, per jt
#pragma unroll
    for (int jt = 0; jt < 7; ++jt) {
        int jb = jt * 16 + l4 * 4;
        unsigned int p = 0;
#pragma unroll
        for (int r = 0; r < 4; ++r) p |= (unsigned)tok_code(jb + r < 98 ? jb + r : 0) << (8 * r);
        jcp[jt] = p;
    }

    unsigned short* myP = p_lds + wv * 1280;   // [2][16][40]

    for (int pass = 0; pass < 2; ++pass) {
        int task = wv + (pass << 4);
        if (task >= 28) break;
        int h  = task / 7;
        int it = task - h * 7;
        const int i_tok = it * 16 + lc;
        const unsigned int ci = (unsigned)tok_code(i_tok < 98 ? i_tok : 0);
        const unsigned short* brow = biasL + (h * 112 + i_tok) * 112;
        const bf16x8 qfrag = *(bf16x8*)(q_lds + swz(i_tok, h * 32 + l4 * 8));

        f32x4 s[7];
#pragma unroll
        for (int jt = 0; jt < 7; ++jt) {
            ushort4 bb = *(const ushort4*)(brow + jt * 16 + l4 * 4);
            f32x4 c;
            c[0] = __builtin_bit_cast(float, (unsigned)bb.x << 16) + mterm(jcp[jt], 0,  ci, cls);
            c[1] = __builtin_bit_cast(float, (unsigned)bb.y << 16) + mterm(jcp[jt], 8,  ci, cls);
            c[2] = __builtin_bit_cast(float, (unsigned)bb.z << 16) + mterm(jcp[jt], 16, ci, cls);
            c[3] = __builtin_bit_cast(float, (unsigned)bb.w << 16) + mterm(jcp[jt], 24, ci, cls);
            bf16x8 kfrag = *(bf16x8*)(k_lds + swz(jt * 16 + lc, h * 32 + l4 * 8));
            s[jt] = __builtin_amdgcn_mfma_f32_16x16x32_bf16(kfrag, qfrag, c, 0, 0, 0);
        }

        // row max (rows of S^T live across l4 groups): tree + shfl 16/32
        float m = -INFINITY;
#pragma unroll
        for (int jt = 0; jt < 7; ++jt)
            m = fmaxf(m, fmaxf(fmaxf(s[jt][0], s[jt][1]), fmaxf(s[jt][2], s[jt][3])));
        m = fmaxf(m, __shfl_xor(m, 16));
        m = fmaxf(m, __shfl_xor(m, 32));

        float lsum = 0.f;
        f32x4 o0 = {0.f, 0.f, 0.f, 0.f}, o1 = {0.f, 0.f, 0.f, 0.f};
#pragma unroll
        for (int jt4 = 0; jt4 < 4; ++jt4) {
            unsigned short* pb = myP + (jt4 & 1) * 640;
#pragma unroll
            for (int sub = 0; sub < 2; ++sub) {
                int jt = jt4 * 2 + sub;       // 0..7; jt==7 is the j=112..127 pad
                ushort4 hv;
                if (jt < 7) {
                    float p0 = exp2f(s[jt][0] - m);
                    float p1 = exp2f(s[jt][1] - m);
                    float p2 = exp2f(s[jt][2] - m);
                    float p3 = exp2f(s[jt][3] - m);
                    lsum += (p0 + p1) + (p2 + p3);
                    hv.x = f2bf(p0); hv.y = f2bf(p1); hv.z = f2bf(p2); hv.w = f2bf(p3);
                } else {
                    hv.x = 0; hv.y = 0; hv.z = 0; hv.w = 0;
                }
                *(ushort4*)(pb + lc * 40 + sub * 16 + l4 * 4) = hv;
            }
            bf16x8 pfrag = *(bf16x8*)(pb + lc * 40 + l4 * 8);
            bf16x8 va = *(bf16x8*)(vT_lds + swz(h * 32 + lc,      jt4 * 32 + l4 * 8));
            bf16x8 vb = *(bf16x8*)(vT_lds + swz(h * 32 + 16 + lc, jt4 * 32 + l4 * 8));
            o0 = __builtin_amdgcn_mfma_f32_16x16x32_bf16(va, pfrag, o0, 0, 0, 0);
            o1 = __builtin_amdgcn_mfma_f32_16x16x32_bf16(vb, pfrag, o1, 0, 0, 0);
        }
        lsum += __shfl_xor(lsum, 16);
        lsum += __shfl_xor(lsum, 32);

        float inv = 1.0f / lsum;
        ushort4 h0, h1;
        h0.x = f2bf(o0[0] * inv); h0.y = f2bf(o0[1] * inv);
        h0.z = f2bf(o0[2] * inv); h0.w = f2bf(o0[3] * inv);
        h1.x = f2bf(o1[0] * inv); h1.y = f2bf(o1[1] * inv);
        h1.z = f2bf(o1[2] * inv); h1.w = f2bf(o1[3] * inv);
        *(ushort4*)(xo_lds + swz(i_tok, h * 32 + l4 * 4)) = h0;
        *(ushort4*)(xo_lds + swz(i_tok, h * 32 + 16 + l4 * 4)) = h1;
    }
    __syncthreads();

    // ---- Phase 3: y^T = Wproj @ O^T. wave -> ct = wv>>1, token half by wv&1 ----
    {
        const int ct = wv >> 1;
        bf16x8 pw[4];
#pragma unroll
        for (int kt = 0; kt < 4; ++kt)
            pw[kt] = *(const bf16x8*)(wproj + (ct * 16 + lc) * 128 + kt * 32 + l4 * 8);
        f32x4 pbias;
#pragma unroll
        for (int r = 0; r < 4; ++r) pbias[r] = proj_b[ct * 16 + l4 * 4 + r];

        float* ob = out + (size_t)b * 12544;
        const int t0 = (wv & 1) ? 4 : 0, t1 = (wv & 1) ? 7 : 4;
        for (int t = t0; t < t1; ++t) {
            f32x4 acc = pbias;
#pragma unroll
            for (int kt = 0; kt < 4; ++kt) {
                bf16x8 of = *(bf16x8*)(xo_lds + swz(t * 16 + lc, kt * 32 + l4 * 8));
                acc = __builtin_amdgcn_mfma_f32_16x16x32_bf16(pw[kt], of, acc, 0, 0, 0);
            }
            int tok = t * 16 + lc;
            if (tok < 98) {
                float4 st; st.x = acc[0]; st.y = acc[1]; st.z = acc[2]; st.w = acc[3];
                *(float4*)(ob + tok * 128 + ct * 16 + l4 * 4) = st;
            }
        }
    }
}

extern "C" void kernel_launch(void* const* d_in, const int* in_sizes, int n_in,
                              void* d_out, int out_size, void* d_ws, size_t ws_size,
                              hipStream_t stream) {
    const float* x       = (const float*)d_in[0];
    const float* qkv_w   = (const float*)d_in[1];
    const float* qkv_b   = (const float*)d_in[2];
    const float* rpb_tab = (const float*)d_in[3];
    const float* proj_w  = (const float*)d_in[4];
    const float* proj_b  = (const float*)d_in[5];
    const int*   rel_idx = (const int*)d_in[6];
    // d_in[7] (mask) unused: reproduced analytically in-kernel.

    unsigned short* wqkv  = (unsigned short*)d_ws;                   // 384*128 bf16 (98304 B)
    unsigned short* wproj = (unsigned short*)((char*)d_ws + 98304);  // 128*128 bf16 (32768 B)
    unsigned short* biasL = (unsigned short*)((char*)d_ws + 131072); // 4*112*112 bf16 (100352 B)
    float*          out   = (float*)d_out;

    hipLaunchKernelGGL(prep_kernel, dim3(256), dim3(256), 0, stream,
                       qkv_w, proj_w, rpb_tab, rel_idx, wqkv, wproj, biasL);

    const int LDS_BYTES = 159744;
    (void)hipFuncSetAttribute((const void*)swin_main,
                              hipFuncAttributeMaxDynamicSharedMemorySize, LDS_BYTES);
    hipLaunchKernelGGL(swin_main, dim3(2048), dim3(1024), LDS_BYTES, stream,
                       x, qkv_b, proj_b, wqkv, wproj, biasL, out);
}

// Round 4
// 137.334 us; speedup vs baseline: 1.9498x; 1.1443x over previous
//
#include <hip/hip_runtime.h>
#include <math.h>
#include <stdint.h>

// Video Swin shifted-window attention, fully fused, one block per window.
// Round 4: VALU reduction on the round-3 structure (1024 thr / 16 waves):
//  - native __bf16 casts (compiler emits v_cvt_pk_bf16_f32) instead of
//    hand-rolled integer RNE (~4 VALU/elem -> ~0.5)
//  - BIG path (ws-gated): bias+mask+pad pre-resolved per window-class into
//    f32 table bm[8][4][112][112] -> C-operand is one 16B load, zero VALU
//  - fallback small path = round-3 (bf16 bias table + in-kernel mask)

#define LOG2E   1.4426950408889634f
#define MASKNEG (-144.26950408889634f)   // -100 * LOG2E

typedef __attribute__((ext_vector_type(8))) short bf16x8;
typedef __attribute__((ext_vector_type(4))) float f32x4;

__device__ __forceinline__ unsigned short cvt1(float f) {
    __bf16 h = (__bf16)f;
    return __builtin_bit_cast(unsigned short, h);
}
__device__ __forceinline__ unsigned cvt2(float lo, float hi) {
    return (unsigned)cvt1(lo) | ((unsigned)cvt1(hi) << 16);
}

// token region code for the shifted-window mask (WIN=(2,7,7), SHIFT=(1,3,3))
__device__ __forceinline__ int tok_code(int t) {
    int pd = t / 49;
    int r  = t - pd * 49;
    int ph = r / 7;
    int pw = r - ph * 7;
    return (pd >= 1 ? 1 : 0) | (ph >= 4 ? 2 : 0) | (pw >= 4 ? 4 : 0);
}

__device__ __forceinline__ float mterm(unsigned pk, int sh, unsigned ci, unsigned cls) {
    return ((((pk >> sh) & 255u) ^ ci) & cls) ? MASKNEG : 0.f;
}

// XOR-swizzled element offset inside a [rows][128]-bf16 LDS tile (16B chunks).
__device__ __forceinline__ int swz(int row, int col) {
    return row * 128 + (((col >> 3) ^ (row & 7)) << 3) + (col & 7);
}

// ---------------- prep: weights -> bf16, bias tables ----------------
template<bool BIG>
__global__ void prep_kernel(const float* __restrict__ qkv_w,
                            const float* __restrict__ proj_w,
                            const float* __restrict__ rpb_table,
                            const int*   __restrict__ rel_index,
                            unsigned short* __restrict__ wqkv,
                            unsigned short* __restrict__ wproj,
                            void* __restrict__ btab) {
    int tid = blockIdx.x * blockDim.x + threadIdx.x;
    int stride = gridDim.x * blockDim.x;
    for (int i = tid; i < 384 * 128; i += stride) wqkv[i]  = cvt1(qkv_w[i]);
    for (int i = tid; i < 128 * 128; i += stride) wproj[i] = cvt1(proj_w[i]);
    if constexpr (BIG) {
        // bm[cls 8][h 4][i 112][j 112] f32: (bias + mask)*LOG2E; j>=98 -> -inf
        float* bm = (float*)btab;
        for (int idx = tid; idx < 32 * 112 * 112; idx += stride) {
            int ch = idx / 12544; int r = idx - ch * 12544;
            int i  = r / 112;     int j = r - i * 112;
            int cls = ch >> 2, h = ch & 3;
            float v;
            if (i < 98) {
                if (j < 98) {
                    float bias = rpb_table[rel_index[i * 98 + j] * 4 + h];
                    bool  msk  = (((unsigned)tok_code(i) ^ (unsigned)tok_code(j)) & (unsigned)cls) != 0;
                    v = bias * LOG2E + (msk ? MASKNEG : 0.f);
                } else v = -INFINITY;
            } else v = 0.f;
            bm[idx] = v;
        }
    } else {
        // biasL[h 4][i 112][j 112] bf16, premult LOG2E; j>=98 -> -inf
        unsigned short* biasL = (unsigned short*)btab;
        for (int idx = tid; idx < 4 * 112 * 112; idx += stride) {
            int h = idx / 12544; int r = idx - h * 12544;
            int i = r / 112;     int j = r - i * 112;
            float v;
            if (i < 98) v = (j < 98) ? rpb_table[rel_index[i * 98 + j] * 4 + h] * LOG2E
                                     : -INFINITY;
            else v = 0.f;
            biasL[idx] = cvt1(v);
        }
    }
}

// ---------------- main fused kernel ----------------
template<bool BIG>
__global__ __launch_bounds__(1024)
void swin_main(const float* __restrict__ x,
               const float* __restrict__ qkv_b,
               const float* __restrict__ proj_b,
               const unsigned short* __restrict__ wqkv,
               const unsigned short* __restrict__ wproj,
               const void* __restrict__ btab,
               float* __restrict__ out)
{
    extern __shared__ unsigned short lds[];
    unsigned short* q_lds  = lds;            // [112][128] bf16, swizzled
    unsigned short* k_lds  = lds + 14336;    // [112][128]
    unsigned short* vT_lds = lds + 28672;    // [128][128] (cols 112..127 zeroed)
    unsigned short* xo_lds = lds + 45056;    // [112][128] x during QKV, O afterwards
    unsigned short* p_lds  = lds + 59392;    // [16 waves][2 buf][16][40]

    const int b    = blockIdx.x;
    const int tid  = threadIdx.x;
    const int wv   = tid >> 6;    // 0..15
    const int lane = tid & 63;
    const int l4   = lane >> 4;   // 0..3
    const int lc   = lane & 15;   // 0..15

    // zero vT pad cols 112..127 (128 rows x 16 cols = 2048 ushorts, 2/thread)
    {
        int idx2 = tid * 2;
        int row  = idx2 >> 4;
        int c    = 112 + (idx2 & 15);
        *(unsigned int*)(vT_lds + swz(row, c)) = 0u;
    }

    // stage x -> xo_lds as bf16 (pad rows 98..111 zeroed)
    {
        const float* xb = x + (size_t)b * 12544;
        for (int idx = tid; idx < 3584; idx += 1024) {
            int tok = idx >> 5;
            int c   = (idx & 31) << 2;
            float4 v;
            if (tok < 98) v = *(const float4*)(xb + tok * 128 + c);
            else { v.x = 0.f; v.y = 0.f; v.z = 0.f; v.w = 0.f; }
            uint2 hv; hv.x = cvt2(v.x, v.y); hv.y = cvt2(v.z, v.w);
            *(uint2*)(xo_lds + swz(tok, c)) = hv;
        }
    }
    __syncthreads();

    // ---- Phase 1: QKV' = Wqkv @ X^T ----
    // wave wv: column-tile ct=wv (q: 0..7 w/ scale, k: 8..15), plus half of a v tile.
    {
        const int ct = wv;
        bf16x8 wf[4];
        f32x4  bias;
        const unsigned short* wrow = wqkv + (ct * 16 + lc) * 128;
#pragma unroll
        for (int kt = 0; kt < 4; ++kt) wf[kt] = *(const bf16x8*)(wrow + kt * 32 + l4 * 8);
#pragma unroll
        for (int r = 0; r < 4; ++r) bias[r] = qkv_b[ct * 16 + l4 * 4 + r];
        const bool  isq = (ct < 8);
        const float qs  = 0.17677669529663689f * LOG2E;  // scale*log2e folded into q
#pragma unroll
        for (int t = 0; t < 7; ++t) {
            bf16x8 xf[4];
#pragma unroll
            for (int kt = 0; kt < 4; ++kt)
                xf[kt] = *(bf16x8*)(xo_lds + swz(t * 16 + lc, kt * 32 + l4 * 8));
            f32x4 acc = bias;
#pragma unroll
            for (int kt = 0; kt < 4; ++kt)
                acc = __builtin_amdgcn_mfma_f32_16x16x32_bf16(wf[kt], xf[kt], acc, 0, 0, 0);
            int tok = t * 16 + lc;
            if (isq) {
                uint2 hv; hv.x = cvt2(acc[0] * qs, acc[1] * qs); hv.y = cvt2(acc[2] * qs, acc[3] * qs);
                *(uint2*)(q_lds + swz(tok, ct * 16 + l4 * 4)) = hv;
            } else {
                uint2 hv; hv.x = cvt2(acc[0], acc[1]); hv.y = cvt2(acc[2], acc[3]);
                *(uint2*)(k_lds + swz(tok, (ct - 8) * 16 + l4 * 4)) = hv;
            }
        }
        // v: wave pair (wv>>1) owns channel block vd, halves split by wv&1
        const int vd = (wv >> 1) * 16;
        bf16x8 wf2[4];
        const unsigned short* wrow2 = wqkv + (256 + vd + lc) * 128;
#pragma unroll
        for (int kt = 0; kt < 4; ++kt) wf2[kt] = *(const bf16x8*)(wrow2 + kt * 32 + l4 * 8);
        f32x4 bias2;
#pragma unroll
        for (int r = 0; r < 4; ++r) bias2[r] = qkv_b[256 + vd + l4 * 4 + r];
        const int t0 = (wv & 1) ? 4 : 0, t1 = (wv & 1) ? 7 : 4;
        for (int t = t0; t < t1; ++t) {
            bf16x8 xf[4];
#pragma unroll
            for (int kt = 0; kt < 4; ++kt)
                xf[kt] = *(bf16x8*)(xo_lds + swz(t * 16 + lc, kt * 32 + l4 * 8));
            f32x4 acc = bias2;
#pragma unroll
            for (int kt = 0; kt < 4; ++kt)
                acc = __builtin_amdgcn_mfma_f32_16x16x32_bf16(wf2[kt], xf[kt], acc, 0, 0, 0);
            int tok = t * 16 + lc;
            unsigned d0 = cvt2(acc[0], acc[1]);
            unsigned d1 = cvt2(acc[2], acc[3]);
            int rb = vd + l4 * 4;
            vT_lds[swz(rb + 0, tok)] = (unsigned short)d0;
            vT_lds[swz(rb + 1, tok)] = (unsigned short)(d0 >> 16);
            vT_lds[swz(rb + 2, tok)] = (unsigned short)d1;
            vT_lds[swz(rb + 3, tok)] = (unsigned short)(d1 >> 16);
        }
    }
    __syncthreads();

    // ---- Phase 2: attention. 28 tasks (head,i-tile) over 16 waves, 2 passes ----
    const int wi  = b & 255;
    const unsigned int cls =
        ((wi >> 6) == 3 ? 1u : 0u) | (((wi >> 3) & 7) == 7 ? 2u : 0u) | ((wi & 7) == 7 ? 4u : 0u);

    unsigned int jcp[7];   // packed region codes (small path only)
    if constexpr (!BIG) {
#pragma unroll
        for (int jt = 0; jt < 7; ++jt) {
            int jb = jt * 16 + l4 * 4;
            unsigned int p = 0;
#pragma unroll
            for (int r = 0; r < 4; ++r) p |= (unsigned)tok_code(jb + r < 98 ? jb + r : 0) << (8 * r);
            jcp[jt] = p;
        }
    }

    unsigned short* myP = p_lds + wv * 1280;   // [2][16][40]

    for (int pass = 0; pass < 2; ++pass) {
        int task = wv + (pass << 4);
        if (task >= 28) break;
        int h  = task / 7;
        int it = task - h * 7;
        const int i_tok = it * 16 + lc;
        const bf16x8 qfrag = *(bf16x8*)(q_lds + swz(i_tok, h * 32 + l4 * 8));

        // prefetch all 7 C-operands (bias+mask) into regs so loads overlap
        f32x4 cvec[7];
        if constexpr (BIG) {
            const float* bmrow = (const float*)btab + ((size_t)((int)cls * 4 + h) * 112 + i_tok) * 112;
#pragma unroll
            for (int jt = 0; jt < 7; ++jt)
                cvec[jt] = *(const f32x4*)(bmrow + jt * 16 + l4 * 4);
        } else {
            const unsigned short* brow = (const unsigned short*)btab + (h * 112 + i_tok) * 112;
            const unsigned int ci = (unsigned)tok_code(i_tok < 98 ? i_tok : 0);
            ushort4 bb[7];
#pragma unroll
            for (int jt = 0; jt < 7; ++jt)
                bb[jt] = *(const ushort4*)(brow + jt * 16 + l4 * 4);
#pragma unroll
            for (int jt = 0; jt < 7; ++jt) {
                cvec[jt][0] = __builtin_bit_cast(float, (unsigned)bb[jt].x << 16) + mterm(jcp[jt], 0,  ci, cls);
                cvec[jt][1] = __builtin_bit_cast(float, (unsigned)bb[jt].y << 16) + mterm(jcp[jt], 8,  ci, cls);
                cvec[jt][2] = __builtin_bit_cast(float, (unsigned)bb[jt].z << 16) + mterm(jcp[jt], 16, ci, cls);
                cvec[jt][3] = __builtin_bit_cast(float, (unsigned)bb[jt].w << 16) + mterm(jcp[jt], 24, ci, cls);
            }
        }

        f32x4 s[7];
#pragma unroll
        for (int jt = 0; jt < 7; ++jt) {
            bf16x8 kfrag = *(bf16x8*)(k_lds + swz(jt * 16 + lc, h * 32 + l4 * 8));
            s[jt] = __builtin_amdgcn_mfma_f32_16x16x32_bf16(kfrag, qfrag, cvec[jt], 0, 0, 0);
        }

        // row max (rows of S^T live across l4 groups): tree + shfl 16/32
        float m = -INFINITY;
#pragma unroll
        for (int jt = 0; jt < 7; ++jt)
            m = fmaxf(m, fmaxf(fmaxf(s[jt][0], s[jt][1]), fmaxf(s[jt][2], s[jt][3])));
        m = fmaxf(m, __shfl_xor(m, 16));
        m = fmaxf(m, __shfl_xor(m, 32));

        float lsum = 0.f;
        f32x4 o0 = {0.f, 0.f, 0.f, 0.f}, o1 = {0.f, 0.f, 0.f, 0.f};
#pragma unroll
        for (int jt4 = 0; jt4 < 4; ++jt4) {
            unsigned short* pb = myP + (jt4 & 1) * 640;
#pragma unroll
            for (int sub = 0; sub < 2; ++sub) {
                int jt = jt4 * 2 + sub;       // 0..7; jt==7 is the j=112..127 pad
                uint2 pv;
                if (jt < 7) {
                    float p0 = exp2f(s[jt][0] - m);
                    float p1 = exp2f(s[jt][1] - m);
                    float p2 = exp2f(s[jt][2] - m);
                    float p3 = exp2f(s[jt][3] - m);
                    lsum += (p0 + p1) + (p2 + p3);
                    pv.x = cvt2(p0, p1); pv.y = cvt2(p2, p3);
                } else {
                    pv.x = 0u; pv.y = 0u;
                }
                *(uint2*)(pb + lc * 40 + sub * 16 + l4 * 4) = pv;
            }
            bf16x8 pfrag = *(bf16x8*)(pb + lc * 40 + l4 * 8);
            bf16x8 va = *(bf16x8*)(vT_lds + swz(h * 32 + lc,      jt4 * 32 + l4 * 8));
            bf16x8 vb = *(bf16x8*)(vT_lds + swz(h * 32 + 16 + lc, jt4 * 32 + l4 * 8));
            o0 = __builtin_amdgcn_mfma_f32_16x16x32_bf16(va, pfrag, o0, 0, 0, 0);
            o1 = __builtin_amdgcn_mfma_f32_16x16x32_bf16(vb, pfrag, o1, 0, 0, 0);
        }
        lsum += __shfl_xor(lsum, 16);
        lsum += __shfl_xor(lsum, 32);

        float inv = 1.0f / lsum;
        uint2 h0, h1;
        h0.x = cvt2(o0[0] * inv, o0[1] * inv); h0.y = cvt2(o0[2] * inv, o0[3] * inv);
        h1.x = cvt2(o1[0] * inv, o1[1] * inv); h1.y = cvt2(o1[2] * inv, o1[3] * inv);
        *(uint2*)(xo_lds + swz(i_tok, h * 32 + l4 * 4)) = h0;
        *(uint2*)(xo_lds + swz(i_tok, h * 32 + 16 + l4 * 4)) = h1;
    }
    __syncthreads();

    // ---- Phase 3: y^T = Wproj @ O^T. wave -> ct = wv>>1, token half by wv&1 ----
    {
        const int ct = wv >> 1;
        bf16x8 pw[4];
#pragma unroll
        for (int kt = 0; kt < 4; ++kt)
            pw[kt] = *(const bf16x8*)(wproj + (ct * 16 + lc) * 128 + kt * 32 + l4 * 8);
        f32x4 pbias;
#pragma unroll
        for (int r = 0; r < 4; ++r) pbias[r] = proj_b[ct * 16 + l4 * 4 + r];

        float* ob = out + (size_t)b * 12544;
        const int t0 = (wv & 1) ? 4 : 0, t1 = (wv & 1) ? 7 : 4;
        for (int t = t0; t < t1; ++t) {
            f32x4 acc = pbias;
#pragma unroll
            for (int kt = 0; kt < 4; ++kt) {
                bf16x8 of = *(bf16x8*)(xo_lds + swz(t * 16 + lc, kt * 32 + l4 * 8));
                acc = __builtin_amdgcn_mfma_f32_16x16x32_bf16(pw[kt], of, acc, 0, 0, 0);
            }
            int tok = t * 16 + lc;
            if (tok < 98) {
                float4 st; st.x = acc[0]; st.y = acc[1]; st.z = acc[2]; st.w = acc[3];
                *(float4*)(ob + tok * 128 + ct * 16 + l4 * 4) = st;
            }
        }
    }
}

extern "C" void kernel_launch(void* const* d_in, const int* in_sizes, int n_in,
                              void* d_out, int out_size, void* d_ws, size_t ws_size,
                              hipStream_t stream) {
    const float* x       = (const float*)d_in[0];
    const float* qkv_w   = (const float*)d_in[1];
    const float* qkv_b   = (const float*)d_in[2];
    const float* rpb_tab = (const float*)d_in[3];
    const float* proj_w  = (const float*)d_in[4];
    const float* proj_b  = (const float*)d_in[5];
    const int*   rel_idx = (const int*)d_in[6];
    // d_in[7] (mask) unused: reproduced analytically into the tables.

    unsigned short* wqkv  = (unsigned short*)d_ws;                   // 384*128 bf16 (98304 B)
    unsigned short* wproj = (unsigned short*)((char*)d_ws + 98304);  // 128*128 bf16 (32768 B)
    void*           btab  = (void*)((char*)d_ws + 131072);           // bias table
    float*          out   = (float*)d_out;

    const bool big = ws_size >= (size_t)(131072 + 32 * 112 * 112 * 4);  // 1,736,704 B
    const int LDS_BYTES = 159744;

    if (big) {
        hipLaunchKernelGGL((prep_kernel<true>), dim3(512), dim3(256), 0, stream,
                           qkv_w, proj_w, rpb_tab, rel_idx, wqkv, wproj, btab);
        (void)hipFuncSetAttribute((const void*)(swin_main<true>),
                                  hipFuncAttributeMaxDynamicSharedMemorySize, LDS_BYTES);
        hipLaunchKernelGGL((swin_main<true>), dim3(2048), dim3(1024), LDS_BYTES, stream,
                           x, qkv_b, proj_b, wqkv, wproj, btab, out);
    } else {
        hipLaunchKernelGGL((prep_kernel<false>), dim3(512), dim3(256), 0, stream,
                           qkv_w, proj_w, rpb_tab, rel_idx, wqkv, wproj, btab);
        (void)hipFuncSetAttribute((const void*)(swin_main<false>),
                                  hipFuncAttributeMaxDynamicSharedMemorySize, LDS_BYTES);
        hipLaunchKernelGGL((swin_main<false>), dim3(2048), dim3(1024), LDS_BYTES, stream,
                           x, qkv_b, proj_b, wqkv, wproj, btab, out);
    }
}